// Round 2
// baseline (124.970 us; speedup 1.0000x reference)
//
#include <hip/hip_runtime.h>

#define HH 256
#define WW 256
#define NPIX (HH * WW)

// The network collapses algebraically:
//  - FPS always selects point 0 (dist[0]=0 is the persistent argmin) -> 500
//    identical selected points.
//  - All rows through the pointnet are identical, so the dense BatchNorms
//    (axes=(0,)) output exactly their beta: h=relu(be4), then relu(be5).
//  - feats (all rows equal) = relu(be5) @ Wd3^T + bd3  =: feats0
//  - out[c,p] = Ws[c,:6] . pc[p] + (bs[c] + Ws[c,6:] . feats0)  inside box,
//    0 outside.  pc = [ invK @ (u+.5, v+.5, 1) * z, rgb ].
//
// setup_kernel: invert intrinsic (f64), feats0 (128-vec GEMV), const80.
//   ws[0..8] = invK row-major, ws[16..95] = const80.
__global__ __launch_bounds__(512) void setup_kernel(
    const float* __restrict__ intrinsic,
    const float* __restrict__ be5,
    const float* __restrict__ Wd3,
    const float* __restrict__ bd3,
    const float* __restrict__ Ws,
    const float* __restrict__ bs,
    float* __restrict__ ws) {
    __shared__ float part[512];
    __shared__ float feats0[128];
    int t = threadIdx.x;
    if (t == 0) {
        double a = intrinsic[0], b = intrinsic[1], c = intrinsic[2];
        double d = intrinsic[3], e = intrinsic[4], f = intrinsic[5];
        double g = intrinsic[6], h = intrinsic[7], i = intrinsic[8];
        double det = a*(e*i - f*h) - b*(d*i - f*g) + c*(d*h - e*g);
        double inv[9] = {
            (e*i - f*h), -(b*i - c*h),  (b*f - c*e),
           -(d*i - f*g),  (a*i - c*g), -(a*f - c*d),
            (d*h - e*g), -(a*h - b*g),  (a*e - b*d)
        };
        for (int m = 0; m < 9; ++m) ws[m] = (float)(inv[m] / det);
    }
    // feats0[j] = bd3[j] + sum_k relu(be5[k]) * Wd3[j*256+k]
    // 512 threads = 128 j  x  4 k-chunks of 64; float4 loads (16/thread).
    int j = t & 127;
    int ck = t >> 7;              // 0..3
    const float4* w4 = (const float4*)(Wd3 + j * 256 + ck * 64);
    float acc = 0.0f;
    #pragma unroll
    for (int q = 0; q < 16; ++q) {
        float4 w = w4[q];
        int k0 = ck * 64 + q * 4;
        acc = fmaf(fmaxf(be5[k0 + 0], 0.0f), w.x, acc);
        acc = fmaf(fmaxf(be5[k0 + 1], 0.0f), w.y, acc);
        acc = fmaf(fmaxf(be5[k0 + 2], 0.0f), w.z, acc);
        acc = fmaf(fmaxf(be5[k0 + 3], 0.0f), w.w, acc);
    }
    part[t] = acc;
    __syncthreads();
    if (ck == 0)
        feats0[j] = bd3[j] + part[j] + part[j + 128] + part[j + 256] + part[j + 384];
    __syncthreads();
    // const80[c] = bs[c] + sum_j feats0[j] * Ws[c*134 + 6 + j]
    // 320 threads = 80 c x 4 j-chunks of 32.
    if (t < 320) {
        int cc = t >> 2, s = t & 3;
        float a2 = 0.0f;
        #pragma unroll
        for (int q = 0; q < 32; ++q) {
            int jj = s * 32 + q;
            a2 = fmaf(feats0[jj], Ws[cc * 134 + 6 + jj], a2);
        }
        part[t] = a2;
    }
    __syncthreads();
    if (t < 80)
        ws[16 + t] = bs[t] + part[4 * t] + part[4 * t + 1] + part[4 * t + 2] + part[4 * t + 3];
}

// Main: one thread per pixel. 80 coalesced channel-strided stores/thread.
__global__ __launch_bounds__(256) void seg_kernel(
    const float* __restrict__ rgb, const float* __restrict__ depth,
    const int* __restrict__ box, const float* __restrict__ Ws,
    const float* __restrict__ ws, float* __restrict__ out) {
    __shared__ float sW[80][6];
    __shared__ float sC[80];
    __shared__ float sik[9];
    int t = threadIdx.x;
    for (int i = t; i < 480; i += 256) sW[i / 6][i % 6] = Ws[(i / 6) * 134 + (i % 6)];
    if (t < 80) sC[t] = ws[16 + t];
    if (t >= 96 && t < 105) sik[t - 96] = ws[t - 96];
    __syncthreads();

    int x1 = box[0], y1 = box[1], x2 = box[2], y2 = box[3];
    int row = blockIdx.x;   // 0..255
    int col = t;            // 0..255
    int p = row * WW + col;
    bool inbox = (row >= x1 && row < x2 && col >= y1 && col < y2);

    float q0 = 0.f, q1 = 0.f, q2 = 0.f, q3 = 0.f, q4 = 0.f, q5 = 0.f;
    if (inbox) {
        float z = depth[p];
        float u = (float)(col - y1) + 0.5f;   // box-relative, per reference
        float v = (float)(row - x1) + 0.5f;
        q0 = (u * sik[0] + v * sik[1] + sik[2]) * z;
        q1 = (u * sik[3] + v * sik[4] + sik[5]) * z;
        q2 = (u * sik[6] + v * sik[7] + sik[8]) * z;
        q3 = rgb[p * 3 + 0];
        q4 = rgb[p * 3 + 1];
        q5 = rgb[p * 3 + 2];
    }

    #pragma unroll
    for (int c = 0; c < 80; ++c) {
        float val = 0.0f;
        if (inbox) {
            val = sC[c];
            val = fmaf(sW[c][0], q0, val);
            val = fmaf(sW[c][1], q1, val);
            val = fmaf(sW[c][2], q2, val);
            val = fmaf(sW[c][3], q3, val);
            val = fmaf(sW[c][4], q4, val);
            val = fmaf(sW[c][5], q5, val);
        }
        out[c * NPIX + p] = val;
    }
}

extern "C" void kernel_launch(void* const* d_in, const int* in_sizes, int n_in,
                              void* d_out, int out_size, void* d_ws, size_t ws_size,
                              hipStream_t stream) {
    const float* rgb       = (const float*)d_in[0];
    const float* depth     = (const float*)d_in[1];
    const float* intrinsic = (const float*)d_in[2];
    const int*   box       = (const int*)d_in[3];
    const float* be5       = (const float*)d_in[23];
    const float* Wd3       = (const float*)d_in[24];
    const float* bd3       = (const float*)d_in[25];
    const float* Ws        = (const float*)d_in[26];
    const float* bs        = (const float*)d_in[27];
    float* ws  = (float*)d_ws;
    float* out = (float*)d_out;

    setup_kernel<<<1, 512, 0, stream>>>(intrinsic, be5, Wd3, bd3, Ws, bs, ws);
    seg_kernel<<<256, 256, 0, stream>>>(rgb, depth, box, Ws, ws, out);
}